// Round 14
// baseline (49.272 us; speedup 1.0000x reference)
//
#include <hip/hip_runtime.h>
#include <hip/hip_bf16.h>

// LBONorm: fused LayerNorm + low-rank diffusion smoothing.
// rows = B*S = 16384, d = 2048 (fp32), rank = 8.
// Block = 256 thr (4 waves) owns ROWS_PB rows; thread t owns cols {4t.., 1024+4t..}.
// R1/R8: launch_bounds cap < demand -> spill. Use (256,2) always.
// R4: DPP wave-reduce: 81.5 -> 57.6. R9: split-phase batching: -> 52.8.
// R12: stage-major fused v_add_f32_dpp (hazard-safe): -> 48.7, VALUBusy 40->30%.
// R13: V-before-h load order: null -> setup overlap wasn't the path.
// R14 theory: only ~1.5 blocks/CU co-resident (Occ 19%) with burst-structured
//   blocks {load burst -> compute -> store burst} -> pipes never overlap
//   across blocks. Fix: ROWS_PB 8->4 (grid 4096, half lifetime, 2x block
//   concurrency) KEEPING (256,2)/no-atomics/split-phase (R8's confounds
//   removed); hx register pressure also drops 64->32 regs.

constexpr int D       = 2048;
constexpr int RANK    = 8;
constexpr int BLOCK   = 256;
constexpr int ROWS_PB = 4;
constexpr float LN_EPS = 1e-5f;

using f2  = __attribute__((ext_vector_type(2))) float;
using f4v = __attribute__((ext_vector_type(4))) float;

__device__ __forceinline__ f2 f2fma(f2 a, f2 b, f2 c) {
    return __builtin_elementwise_fma(a, b, c);
}

// NT store: no cache allocate (write stream is touch-once).
__device__ __forceinline__ void nt_store4(float* p, float x, float y, float z, float w) {
    f4v v = {x, y, z, w};
    __builtin_nontemporal_store(v, reinterpret_cast<f4v*>(p));
}

// Barrier draining ONLY lgkmcnt (LDS) -- global loads/stores stay in flight.
__device__ __forceinline__ void barrier_lds() {
    asm volatile("s_waitcnt lgkmcnt(0)\n\ts_barrier" ::: "memory");
}

// Ordered horizontal add feeding the DPP stages (asm program order guarantees
// the first DPP read of each value is >= N instructions after its write).
__device__ __forceinline__ float ordadd(float a, float b) {
    float r;
    asm volatile("v_add_f32 %0, %1, %2" : "=v"(r) : "v"(a), "v"(b));
    return r;
}

// One DPP stage applied across an N-element array (stage-major => same-reg
// DPP writes are N apart; hazard needs 2).
#define DPP_STAGE(v, N, MODS)                                                   \
    _Pragma("unroll")                                                           \
    for (int _n = 0; _n < N; ++_n)                                              \
        asm volatile("v_add_f32_dpp %0, %0, %0 " MODS : "+v"(v[_n]));

// Full 64-lane sum of N independent values; totals valid in lane 63.
template<int N>
__device__ __forceinline__ void dpp_sum64_batch(float (&v)[N]) {
    static_assert(N >= 4, "need N>=4 for hazard distance");
    DPP_STAGE(v, N, "row_shr:1 row_mask:0xf bank_mask:0xf bound_ctrl:0")
    DPP_STAGE(v, N, "row_shr:2 row_mask:0xf bank_mask:0xf bound_ctrl:0")
    DPP_STAGE(v, N, "row_shr:4 row_mask:0xf bank_mask:0xf bound_ctrl:0")
    DPP_STAGE(v, N, "row_shr:8 row_mask:0xf bank_mask:0xf bound_ctrl:0")
    DPP_STAGE(v, N, "row_bcast:15 row_mask:0xa bank_mask:0xf bound_ctrl:0")
    DPP_STAGE(v, N, "row_bcast:31 row_mask:0xc bank_mask:0xf bound_ctrl:0")
}

// 4-lane group totals (all 4 lanes get the sum) of N independent values.
template<int N>
__device__ __forceinline__ void qp_sum4_batch(float (&v)[N]) {
    static_assert(N >= 4, "need N>=4 for hazard distance");
    asm volatile("s_nop 1");
    DPP_STAGE(v, N, "quad_perm:[1,0,3,2] row_mask:0xf bank_mask:0xf bound_ctrl:0")
    DPP_STAGE(v, N, "quad_perm:[2,3,0,1] row_mask:0xf bank_mask:0xf bound_ctrl:0")
}

__global__ __launch_bounds__(BLOCK, 2)
void lbonorm_kernel(const float* __restrict__ h,
                    const float* __restrict__ gamma,
                    const float* __restrict__ beta,
                    const float* __restrict__ V,
                    const float* __restrict__ eta_p,
                    float* __restrict__ out,
                    float* __restrict__ e_out)
{
    const int t    = threadIdx.x;
    const int lane = t & 63;
    const int wave = t >> 6;

    const int c0 = t * 4;
    const int c1 = D / 2 + t * 4;

    // red[row][wave][12]: {s, s2, dot0..7, pad, pad}
    __shared__ __align__(16) float red[ROWS_PB][4][12];
    __shared__ __align__(16) float ered[4][RANK];   // vsum staging + e partials

    const size_t row0 = (size_t)blockIdx.x * ROWS_PB;

    // ---- V / gamma / beta first (setup waits only on these); h after.
    f2 vreg[4][RANK];
    #pragma unroll
    for (int r = 0; r < RANK; ++r) {
        float4 a = *reinterpret_cast<const float4*>(V + (size_t)r * D + c0);
        float4 b = *reinterpret_cast<const float4*>(V + (size_t)r * D + c1);
        vreg[0][r] = f2{a.x, a.y}; vreg[1][r] = f2{a.z, a.w};
        vreg[2][r] = f2{b.x, b.y}; vreg[3][r] = f2{b.z, b.w};
    }
    const float4 g0 = *reinterpret_cast<const float4*>(gamma + c0);
    const float4 g1 = *reinterpret_cast<const float4*>(gamma + c1);
    const float4 bb0 = *reinterpret_cast<const float4*>(beta + c0);
    const float4 bb1 = *reinterpret_cast<const float4*>(beta + c1);
    const f2 gam[4] = {f2{g0.x,g0.y}, f2{g0.z,g0.w}, f2{g1.x,g1.y}, f2{g1.z,g1.w}};
    const f2 bet[4] = {f2{bb0.x,bb0.y}, f2{bb0.z,bb0.w}, f2{bb1.x,bb1.y}, f2{bb1.z,bb1.w}};
    const float eta = fminf(fmaxf(eta_p[0], 0.0f), 0.5f);

    // ---- all ROWS_PB rows' h loads (128 B/lane in flight)
    float4 hx[ROWS_PB][2];
    #pragma unroll
    for (int r = 0; r < ROWS_PB; ++r) {
        hx[r][0] = *reinterpret_cast<const float4*>(h + (row0 + r) * (size_t)D + c0);
        hx[r][1] = *reinterpret_cast<const float4*>(h + (row0 + r) * (size_t)D + c1);
    }

    // ---- per-rank column sums of V (staged in ered; ONE barrier)
    float vsum[RANK];
    {
        float vs[RANK];
        #pragma unroll
        for (int r = 0; r < RANK; ++r) {
            f2 v = (vreg[0][r] + vreg[1][r]) + (vreg[2][r] + vreg[3][r]);
            vs[r] = ordadd(v.x, v.y);
        }
        dpp_sum64_batch(vs);
        if (lane == 63) {
            float4* dst = reinterpret_cast<float4*>(&ered[wave][0]);
            dst[0] = make_float4(vs[0], vs[1], vs[2], vs[3]);
            dst[1] = make_float4(vs[4], vs[5], vs[6], vs[7]);
        }
        barrier_lds();
        const float4* src = reinterpret_cast<const float4*>(&ered[lane & 3][0]);
        const float4 qa = src[0], qb = src[1];
        float qv[8] = {qa.x, qa.y, qa.z, qa.w, qb.x, qb.y, qb.z, qb.w};
        qp_sum4_batch(qv);
        #pragma unroll
        for (int k = 0; k < RANK; ++k) vsum[k] = qv[k];
        // no second barrier: phase 1 writes red[], not ered; ered is reused
        // only after the big phase-1 barrier below.
    }

    // ==== PHASE 1: all rows' partials + batched DPP reduce, no inner barrier
    #pragma unroll
    for (int r = 0; r < ROWS_PB; ++r) {
        const f2 h2[4] = {f2{hx[r][0].x, hx[r][0].y}, f2{hx[r][0].z, hx[r][0].w},
                          f2{hx[r][1].x, hx[r][1].y}, f2{hx[r][1].z, hx[r][1].w}};
        float vals[10];
        {
            f2 s  = (h2[0] + h2[1]) + (h2[2] + h2[3]);
            f2 s2 = f2fma(h2[0], h2[0], f2fma(h2[1], h2[1],
                    f2fma(h2[2], h2[2], h2[3] * h2[3])));
            vals[0] = ordadd(s.x, s.y);
            vals[1] = ordadd(s2.x, s2.y);
            #pragma unroll
            for (int k = 0; k < RANK; ++k) {
                f2 d = f2fma(h2[0], vreg[0][k], f2fma(h2[1], vreg[1][k],
                       f2fma(h2[2], vreg[2][k], h2[3] * vreg[3][k])));
                vals[2 + k] = ordadd(d.x, d.y);
            }
        }
        dpp_sum64_batch(vals);

        if (lane == 63) {
            float4* dst = reinterpret_cast<float4*>(&red[r][wave][0]);
            dst[0] = make_float4(vals[0], vals[1], vals[2], vals[3]);
            dst[1] = make_float4(vals[4], vals[5], vals[6], vals[7]);
            dst[2] = make_float4(vals[8], vals[9], 0.f, 0.f);
        }
    }

    barrier_lds();   // THE barrier: all rows' partials visible (also fences ered reuse)

    // ==== PHASE 2: all rows' combine + epilogue; e partials deferred
    float er[ROWS_PB];
    #pragma unroll
    for (int r = 0; r < ROWS_PB; ++r) {
        const float4* src = reinterpret_cast<const float4*>(&red[r][lane & 3][0]);
        const float4 q0 = src[0], q1 = src[1], q2 = src[2];
        float qv[10] = {q0.x, q0.y, q0.z, q0.w, q1.x, q1.y, q1.z, q1.w, q2.x, q2.y};
        qp_sum4_batch(qv);

        const float mu  = qv[0] * (1.0f / D);
        const float var = fmaxf(qv[1] * (1.0f / D) - mu * mu, 0.0f);
        const float inv = rsqrtf(var + LN_EPS);
        f2 c2[RANK];
        #pragma unroll
        for (int k = 0; k < RANK; ++k) {
            const float c = inv * (qv[2 + k] - mu * vsum[k]);
            c2[k] = f2{c, c};
        }

        const f2 h2[4] = {f2{hx[r][0].x, hx[r][0].y}, f2{hx[r][0].z, hx[r][0].w},
                          f2{hx[r][1].x, hx[r][1].y}, f2{hx[r][1].z, hx[r][1].w}};
        const f2 inv2  = f2{inv, inv};
        const f2 nmi2  = f2{-mu * inv, -mu * inv};
        const f2 neta2 = f2{-eta, -eta};
        f2 e2 = f2{0.f, 0.f};
        f2 ov[4];
        #pragma unroll
        for (int k = 0; k < 4; ++k) {
            const f2 hh = f2fma(h2[k], inv2, nmi2);
            f2 pr = c2[0] * vreg[k][0];
            #pragma unroll
            for (int q = 1; q < RANK; ++q) pr = f2fma(c2[q], vreg[k][q], pr);
            const f2 dl = hh - pr;
            e2 = f2fma(dl, dl, e2);
            const f2 sm = f2fma(neta2, dl, hh);
            ov[k] = f2fma(sm, gam[k], bet[k]);
        }

        float* orow = out + (row0 + r) * (size_t)D;
        nt_store4(orow + c0, ov[0].x, ov[0].y, ov[1].x, ov[1].y);
        nt_store4(orow + c1, ov[2].x, ov[2].y, ov[3].x, ov[3].y);

        er[r] = ordadd(e2.x, e2.y);
    }

    // ---- batched e_curv reduce for all rows (reuses ered; fenced by barrier)
    dpp_sum64_batch(er);
    if (lane == 63) {
        float4* dst = reinterpret_cast<float4*>(&ered[wave][0]);
        dst[0] = make_float4(er[0], er[1], er[2], er[3]);
    }
    barrier_lds();
    if (t < ROWS_PB) {
        const float e = (ered[0][t] + ered[1][t]) + (ered[2][t] + ered[3][t]);
        e_out[row0 + t] = e;
    }
}

extern "C" void kernel_launch(void* const* d_in, const int* in_sizes, int n_in,
                              void* d_out, int out_size, void* d_ws, size_t ws_size,
                              hipStream_t stream) {
    const float* h     = (const float*)d_in[0];
    const float* gamma = (const float*)d_in[1];
    const float* beta  = (const float*)d_in[2];
    const float* V     = (const float*)d_in[3];
    const float* eta   = (const float*)d_in[4];
    float* out = (float*)d_out;

    const int d = in_sizes[1];                       // 2048
    const long long rows = in_sizes[0] / d;          // 16384
    float* e_out = out + (size_t)rows * d;

    dim3 grid((unsigned)(rows / ROWS_PB));
    lbonorm_kernel<<<grid, BLOCK, 0, stream>>>(h, gamma, beta, V, eta, out, e_out);
}

// Round 15
// 49.111 us; speedup vs baseline: 1.0033x; 1.0033x over previous
//
#include <hip/hip_runtime.h>
#include <hip/hip_bf16.h>

// LBONorm: fused LayerNorm + low-rank diffusion smoothing.
// rows = B*S = 16384, d = 2048 (fp32), rank = 8.
// Block = 256 thr (4 waves) owns 32 rows = 8 chunks x 4 rows, double-buffered.
// R1/R8: launch_bounds cap < demand -> spill. R4: DPP reduce. R9: split-phase.
// R12: stage-major fused v_add_f32_dpp (hazard-safe): 48.7 us.
// R13 (load order), R14 (2x block concurrency): null -> inter-block overlap
//   can't fix the burst structure.
// R15 theory: fillBufferAligned hits 7 TB/s on this chip; our block issues ONE
//   load burst then computes ~4us with the memory pipe idle. Fix: in-block
//   software pipeline -- 8 chunks/block, register double-buffer; chunk c+1's
//   loads issue before chunk c's compute (barrier_lds keeps them in flight,
//   compiler emits counted vmcnt). Loads flow continuously; V/setup amortize
//   over 32 rows; grid 512 = 2 blocks/CU.

constexpr int D       = 2048;
constexpr int RANK    = 8;
constexpr int BLOCK   = 256;
constexpr int ROWS_PC = 4;    // rows per chunk
constexpr int NCHUNK  = 8;    // chunks per block -> 32 rows/block
constexpr float LN_EPS = 1e-5f;

using f2  = __attribute__((ext_vector_type(2))) float;
using f4v = __attribute__((ext_vector_type(4))) float;

__device__ __forceinline__ f2 f2fma(f2 a, f2 b, f2 c) {
    return __builtin_elementwise_fma(a, b, c);
}

// NT store: no cache allocate (write stream is touch-once).
__device__ __forceinline__ void nt_store4(float* p, float x, float y, float z, float w) {
    f4v v = {x, y, z, w};
    __builtin_nontemporal_store(v, reinterpret_cast<f4v*>(p));
}

// Barrier draining ONLY lgkmcnt (LDS) -- global loads/stores stay in flight.
__device__ __forceinline__ void barrier_lds() {
    asm volatile("s_waitcnt lgkmcnt(0)\n\ts_barrier" ::: "memory");
}

// Ordered horizontal add feeding the DPP stages (asm program order guarantees
// the first DPP read of each value is >= N instructions after its write).
__device__ __forceinline__ float ordadd(float a, float b) {
    float r;
    asm volatile("v_add_f32 %0, %1, %2" : "=v"(r) : "v"(a), "v"(b));
    return r;
}

// One DPP stage applied across an N-element array (stage-major => same-reg
// DPP writes are N apart; hazard needs 2).
#define DPP_STAGE(v, N, MODS)                                                   \
    _Pragma("unroll")                                                           \
    for (int _n = 0; _n < N; ++_n)                                              \
        asm volatile("v_add_f32_dpp %0, %0, %0 " MODS : "+v"(v[_n]));

// Full 64-lane sum of N independent values; totals valid in lane 63.
template<int N>
__device__ __forceinline__ void dpp_sum64_batch(float (&v)[N]) {
    static_assert(N >= 4, "need N>=4 for hazard distance");
    DPP_STAGE(v, N, "row_shr:1 row_mask:0xf bank_mask:0xf bound_ctrl:0")
    DPP_STAGE(v, N, "row_shr:2 row_mask:0xf bank_mask:0xf bound_ctrl:0")
    DPP_STAGE(v, N, "row_shr:4 row_mask:0xf bank_mask:0xf bound_ctrl:0")
    DPP_STAGE(v, N, "row_shr:8 row_mask:0xf bank_mask:0xf bound_ctrl:0")
    DPP_STAGE(v, N, "row_bcast:15 row_mask:0xa bank_mask:0xf bound_ctrl:0")
    DPP_STAGE(v, N, "row_bcast:31 row_mask:0xc bank_mask:0xf bound_ctrl:0")
}

// 4-lane group totals (all 4 lanes get the sum) of N independent values.
template<int N>
__device__ __forceinline__ void qp_sum4_batch(float (&v)[N]) {
    static_assert(N >= 4, "need N>=4 for hazard distance");
    asm volatile("s_nop 1");
    DPP_STAGE(v, N, "quad_perm:[1,0,3,2] row_mask:0xf bank_mask:0xf bound_ctrl:0")
    DPP_STAGE(v, N, "quad_perm:[2,3,0,1] row_mask:0xf bank_mask:0xf bound_ctrl:0")
}

__global__ __launch_bounds__(BLOCK, 2)
void lbonorm_kernel(const float* __restrict__ h,
                    const float* __restrict__ gamma,
                    const float* __restrict__ beta,
                    const float* __restrict__ V,
                    const float* __restrict__ eta_p,
                    float* __restrict__ out,
                    float* __restrict__ e_out)
{
    const int t    = threadIdx.x;
    const int lane = t & 63;
    const int wave = t >> 6;

    const int c0 = t * 4;
    const int c1 = D / 2 + t * 4;

    // red[buf][row][wave][12]: {s, s2, dot0..7, pad, pad}; 1 barrier/chunk via
    // double buffer (chunk c+2's writes are fenced by chunk c+1's barrier).
    __shared__ __align__(16) float red[2][ROWS_PC][4][12];
    __shared__ __align__(16) float ered[4][ROWS_PC * NCHUNK];  // e partials

    const size_t row0 = (size_t)blockIdx.x * (ROWS_PC * NCHUNK);

    // ---- V / gamma / beta first (setup waits only on these).
    f2 vreg[4][RANK];
    #pragma unroll
    for (int r = 0; r < RANK; ++r) {
        float4 a = *reinterpret_cast<const float4*>(V + (size_t)r * D + c0);
        float4 b = *reinterpret_cast<const float4*>(V + (size_t)r * D + c1);
        vreg[0][r] = f2{a.x, a.y}; vreg[1][r] = f2{a.z, a.w};
        vreg[2][r] = f2{b.x, b.y}; vreg[3][r] = f2{b.z, b.w};
    }
    const float4 g0 = *reinterpret_cast<const float4*>(gamma + c0);
    const float4 g1 = *reinterpret_cast<const float4*>(gamma + c1);
    const float4 bb0 = *reinterpret_cast<const float4*>(beta + c0);
    const float4 bb1 = *reinterpret_cast<const float4*>(beta + c1);
    const f2 gam[4] = {f2{g0.x,g0.y}, f2{g0.z,g0.w}, f2{g1.x,g1.y}, f2{g1.z,g1.w}};
    const f2 bet[4] = {f2{bb0.x,bb0.y}, f2{bb0.z,bb0.w}, f2{bb1.x,bb1.y}, f2{bb1.z,bb1.w}};
    const float eta = fminf(fmaxf(eta_p[0], 0.0f), 0.5f);

    // ---- chunk 0 h loads (double-buffer A)
    float4 hxA[ROWS_PC][2], hxB[ROWS_PC][2];
    #pragma unroll
    for (int r = 0; r < ROWS_PC; ++r) {
        hxA[r][0] = *reinterpret_cast<const float4*>(h + (row0 + r) * (size_t)D + c0);
        hxA[r][1] = *reinterpret_cast<const float4*>(h + (row0 + r) * (size_t)D + c1);
    }

    // ---- per-rank column sums of V (staged in ered; safe: P2(0)'s ered
    // writes happen after B(0), by which every wave has read vsum).
    float vsum[RANK];
    {
        float vs[RANK];
        #pragma unroll
        for (int r = 0; r < RANK; ++r) {
            f2 v = (vreg[0][r] + vreg[1][r]) + (vreg[2][r] + vreg[3][r]);
            vs[r] = ordadd(v.x, v.y);
        }
        dpp_sum64_batch(vs);
        if (lane == 63) {
            float4* dst = reinterpret_cast<float4*>(&ered[wave][0]);
            dst[0] = make_float4(vs[0], vs[1], vs[2], vs[3]);
            dst[1] = make_float4(vs[4], vs[5], vs[6], vs[7]);
        }
        barrier_lds();
        const float4* src = reinterpret_cast<const float4*>(&ered[lane & 3][0]);
        const float4 qa = src[0], qb = src[1];
        float qv[8] = {qa.x, qa.y, qa.z, qa.w, qb.x, qb.y, qb.z, qb.w};
        qp_sum4_batch(qv);
        #pragma unroll
        for (int k = 0; k < RANK; ++k) vsum[k] = qv[k];
    }

    // ==== chunk pipeline: prefetch(c+1) || { P1(c) -> barrier -> P2(c)+stores }
    #pragma unroll
    for (int c = 0; c < NCHUNK; ++c) {
        float4 (&cur)[ROWS_PC][2] = (c & 1) ? hxB : hxA;
        float4 (&nxt)[ROWS_PC][2] = (c & 1) ? hxA : hxB;

        // issue next chunk's loads NOW; they stay in flight through the
        // barrier (lgkmcnt-only) and land during this chunk's compute.
        if (c + 1 < NCHUNK) {
            const size_t nrow = row0 + (size_t)(c + 1) * ROWS_PC;
            #pragma unroll
            for (int r = 0; r < ROWS_PC; ++r) {
                nxt[r][0] = *reinterpret_cast<const float4*>(h + (nrow + r) * (size_t)D + c0);
                nxt[r][1] = *reinterpret_cast<const float4*>(h + (nrow + r) * (size_t)D + c1);
            }
        }

        // ---- P1: partials + batched DPP reduce (waits only cur's loads)
        #pragma unroll
        for (int r = 0; r < ROWS_PC; ++r) {
            const f2 h2[4] = {f2{cur[r][0].x, cur[r][0].y}, f2{cur[r][0].z, cur[r][0].w},
                              f2{cur[r][1].x, cur[r][1].y}, f2{cur[r][1].z, cur[r][1].w}};
            float vals[10];
            {
                f2 s  = (h2[0] + h2[1]) + (h2[2] + h2[3]);
                f2 s2 = f2fma(h2[0], h2[0], f2fma(h2[1], h2[1],
                        f2fma(h2[2], h2[2], h2[3] * h2[3])));
                vals[0] = ordadd(s.x, s.y);
                vals[1] = ordadd(s2.x, s2.y);
                #pragma unroll
                for (int k = 0; k < RANK; ++k) {
                    f2 d = f2fma(h2[0], vreg[0][k], f2fma(h2[1], vreg[1][k],
                           f2fma(h2[2], vreg[2][k], h2[3] * vreg[3][k])));
                    vals[2 + k] = ordadd(d.x, d.y);
                }
            }
            dpp_sum64_batch(vals);

            if (lane == 63) {
                float4* dst = reinterpret_cast<float4*>(&red[c & 1][r][wave][0]);
                dst[0] = make_float4(vals[0], vals[1], vals[2], vals[3]);
                dst[1] = make_float4(vals[4], vals[5], vals[6], vals[7]);
                dst[2] = make_float4(vals[8], vals[9], 0.f, 0.f);
            }
        }

        barrier_lds();   // partials visible; prefetch loads still in flight

        // ---- P2: combine + epilogue + NT stores; e partials -> ered strip
        float er[ROWS_PC];
        #pragma unroll
        for (int r = 0; r < ROWS_PC; ++r) {
            const float4* src = reinterpret_cast<const float4*>(&red[c & 1][r][lane & 3][0]);
            const float4 q0 = src[0], q1 = src[1], q2 = src[2];
            float qv[10] = {q0.x, q0.y, q0.z, q0.w, q1.x, q1.y, q1.z, q1.w, q2.x, q2.y};
            qp_sum4_batch(qv);

            const float mu  = qv[0] * (1.0f / D);
            const float var = fmaxf(qv[1] * (1.0f / D) - mu * mu, 0.0f);
            const float inv = rsqrtf(var + LN_EPS);
            f2 c2[RANK];
            #pragma unroll
            for (int k = 0; k < RANK; ++k) {
                const float cc = inv * (qv[2 + k] - mu * vsum[k]);
                c2[k] = f2{cc, cc};
            }

            const f2 h2[4] = {f2{cur[r][0].x, cur[r][0].y}, f2{cur[r][0].z, cur[r][0].w},
                              f2{cur[r][1].x, cur[r][1].y}, f2{cur[r][1].z, cur[r][1].w}};
            const f2 inv2  = f2{inv, inv};
            const f2 nmi2  = f2{-mu * inv, -mu * inv};
            const f2 neta2 = f2{-eta, -eta};
            f2 e2 = f2{0.f, 0.f};
            f2 ov[4];
            #pragma unroll
            for (int k = 0; k < 4; ++k) {
                const f2 hh = f2fma(h2[k], inv2, nmi2);
                f2 pr = c2[0] * vreg[k][0];
                #pragma unroll
                for (int q = 1; q < RANK; ++q) pr = f2fma(c2[q], vreg[k][q], pr);
                const f2 dl = hh - pr;
                e2 = f2fma(dl, dl, e2);
                const f2 sm = f2fma(neta2, dl, hh);
                ov[k] = f2fma(sm, gam[k], bet[k]);
            }

            float* orow = out + (row0 + (size_t)c * ROWS_PC + r) * (size_t)D;
            nt_store4(orow + c0, ov[0].x, ov[0].y, ov[1].x, ov[1].y);
            nt_store4(orow + c1, ov[2].x, ov[2].y, ov[3].x, ov[3].y);

            er[r] = ordadd(e2.x, e2.y);
        }

        dpp_sum64_batch(er);
        if (lane == 63)
            *reinterpret_cast<float4*>(&ered[wave][c * ROWS_PC]) =
                make_float4(er[0], er[1], er[2], er[3]);
        // no barrier here: next chunk uses red[(c+1)&1]; red[c&1] is rewritten
        // only at chunk c+2, after the (c+1) barrier -> safe.
    }

    // ---- tail: flush all 32 rows' e_curv
    barrier_lds();
    if (t < ROWS_PC * NCHUNK) {
        const float e = (ered[0][t] + ered[1][t]) + (ered[2][t] + ered[3][t]);
        e_out[row0 + t] = e;
    }
}

extern "C" void kernel_launch(void* const* d_in, const int* in_sizes, int n_in,
                              void* d_out, int out_size, void* d_ws, size_t ws_size,
                              hipStream_t stream) {
    const float* h     = (const float*)d_in[0];
    const float* gamma = (const float*)d_in[1];
    const float* beta  = (const float*)d_in[2];
    const float* V     = (const float*)d_in[3];
    const float* eta   = (const float*)d_in[4];
    float* out = (float*)d_out;

    const int d = in_sizes[1];                       // 2048
    const long long rows = in_sizes[0] / d;          // 16384
    float* e_out = out + (size_t)rows * d;

    dim3 grid((unsigned)(rows / (ROWS_PC * NCHUNK)));   // 512
    lbonorm_kernel<<<grid, BLOCK, 0, stream>>>(h, gamma, beta, V, eta, out, e_out);
}